// Round 17
// baseline (80.041 us; speedup 1.0000x reference)
//
#include <hip/hip_runtime.h>
#include <math.h>

#define NROWS 8192
#define NK    4096
#define NE    64
#define NCH   32      // K chunks of 128
#define SLOTB 49152   // 48 KB per slot: x 16K | WH 16K | WL 16K

typedef _Float16 f16x8 __attribute__((ext_vector_type(8)));
typedef float    f32x4 __attribute__((ext_vector_type(4)));

#define CVT8(H, L, V0, V1)                                            \
  do {                                                                \
    H[0] = (_Float16)V0.x; L[0] = (_Float16)(V0.x - (float)H[0]);     \
    H[1] = (_Float16)V0.y; L[1] = (_Float16)(V0.y - (float)H[1]);     \
    H[2] = (_Float16)V0.z; L[2] = (_Float16)(V0.z - (float)H[2]);     \
    H[3] = (_Float16)V0.w; L[3] = (_Float16)(V0.w - (float)H[3]);     \
    H[4] = (_Float16)V1.x; L[4] = (_Float16)(V1.x - (float)H[4]);     \
    H[5] = (_Float16)V1.y; L[5] = (_Float16)(V1.y - (float)H[5]);     \
    H[6] = (_Float16)V1.z; L[6] = (_Float16)(V1.z - (float)H[6]);     \
    H[7] = (_Float16)V1.w; L[7] = (_Float16)(V1.w - (float)H[7]);     \
  } while (0)

__device__ __forceinline__ void gload16(const void* g, void* l) {
  __builtin_amdgcn_global_load_lds(
      (const __attribute__((address_space(1))) unsigned int*)g,
      (__attribute__((address_space(3))) unsigned int*)l, 16, 0, 0);
}

// ---------------------------------------------------------------------------
// Kernel 0: W -> MFMA-fragment-linear f16 hi/lo (verified rounds 4-16); zero
// imp + completion counter. Element ((gk*4 + nt)*64 + lane)*8 + j holds
//   f16( W[nt*16 + (lane&15)][gk*32 + (lane>>4)*8 + j] ), gk = 0..127.
// ---------------------------------------------------------------------------
__global__ __launch_bounds__(256) void k_prep(const float* __restrict__ W,
                                              _Float16* __restrict__ Whi,
                                              _Float16* __restrict__ Wlo,
                                              float* __restrict__ imp,
                                              unsigned* __restrict__ cnt) {
  const int idx = blockIdx.x * 256 + threadIdx.x;   // 0 .. 262143
  if (idx < NE) imp[idx] = 0.f;
  if (idx == NE) *cnt = 0u;
  const int j    = idx & 7;
  const int lane = (idx >> 3) & 63;
  const int nt   = (idx >> 9) & 3;
  const int gk   = idx >> 11;                        // 0..127
  const int e = nt * 16 + (lane & 15);
  const int k = gk * 32 + (lane >> 4) * 8 + j;
  const float w = W[(size_t)e * NK + k];
  const _Float16 wh = (_Float16)w;
  const _Float16 wl = (_Float16)(w - (float)wh);
  Whi[idx] = wh;
  Wlo[idx] = wl;
}

// ---------------------------------------------------------------------------
// Kernel 1 (FUSED, producer-consumer wave specialization — the one untried
// axis after r6-r16 showed every lockstep structure stalls at the same wall):
// grid = 256 (1 block/CU), block = 384 (6 waves).
//   waves 4,5 = PRODUCERS: stage 48 KB chunks (x + W hi/lo, fragment-linear,
//     mappings byte-identical to r14's absmax-0 kernel) via global_load_lds
//     into a 3-slot LDS ring, running 2 chunks ahead; each waits only on ITS
//     OWN vmcnt (valid counting) then release-stores a monotonic flag.
//   waves 0..3 = CONSUMERS: (mi,ni) = 16 rows x 32 experts, full K; spin on
//     both producer flags, 6 MFMA/k-step, then bump monotonic done[slot].
// Producers never block on consumer compute; consumers never issue VMEM.
// Monotonic flags/counters -> no reset race; progress is inductive.
// ---------------------------------------------------------------------------
__global__ __launch_bounds__(384, 1) void k_fused(const float* __restrict__ x,
                                                  const _Float16* __restrict__ Whi,
                                                  const _Float16* __restrict__ Wlo,
                                                  float* __restrict__ out,
                                                  float* __restrict__ imp,
                                                  unsigned* __restrict__ cnt) {
  __shared__ char LDS[3 * SLOTB];     // 144 KB ring
  __shared__ int flagA[3], flagB[3];  // producer-half completion (monotonic)
  __shared__ int done[3];             // consumer completions (monotonic)
  __shared__ int lastflag;

  const int tid  = threadIdx.x;
  const int lane = tid & 63;
  const int wv   = __builtin_amdgcn_readfirstlane(tid >> 6);  // 0..5
  const int l15  = lane & 15;
  const int lhi  = lane >> 4;
  const int rb   = blockIdx.x * 32;

  if (tid < 3) { flagA[tid] = 0; flagB[tid] = 0; done[tid] = 0; }
  __syncthreads();

  if (wv >= 4) {
    // ================= PRODUCER (waves 4,5) =================
    const int p = wv - 4;                       // 0 or 1
    // x base for unit-field decode (row/k pieces added per unit)
    const float* xb = x + (size_t)(rb + l15) * NK + lhi * 8;
#pragma unroll 1
    for (int c = 0; c < NCH; ++c) {
      const int sl = c % 3;
      // wait consumers done with chunk c-3 (monotonic target 4*floor(c/3))
      const int tgt = 4 * (c / 3);
      if (c >= 3)
        while (__hip_atomic_load(&done[sl], __ATOMIC_ACQUIRE,
                                 __HIP_MEMORY_SCOPE_WORKGROUP) < tgt)
          __builtin_amdgcn_s_sleep(1);
      char* slot = LDS + sl * SLOTB;
      const int koff = c * 128;
      const size_t wbase = (size_t)c * 8192;
      // 24 units each: p0 -> flat 0..23 (x0..15, WH0..7); p1 -> 24..47
#pragma unroll
      for (int q = 0; q < 24; ++q) {
        const int f = p * 24 + q;
        if (f < 16) {         // x unit: ks=f>>2, mi=(f>>1)&1, half=f&1
          const int ks = f >> 2, g = f & 3;
          const float* src = xb + (size_t)((g >> 1) * 16) * NK + koff +
                             ks * 32 + (g & 1) * 4;
          gload16(src, slot + f * 1024);
        } else if (f < 32) {  // W-hi unit v = f-16
          gload16(Whi + wbase + (size_t)(f - 16) * 512 + lane * 8,
                  slot + f * 1024);
        } else {              // W-lo unit v = f-32
          gload16(Wlo + wbase + (size_t)(f - 32) * 512 + lane * 8,
                  slot + f * 1024);
        }
      }
      if (c >= 1) {           // chunk c-1's 24 loads landed (24 newer remain)
        asm volatile("s_waitcnt vmcnt(24)" ::: "memory");
        int* fl = p ? flagB : flagA;
        if (lane == 0)
          __hip_atomic_store(&fl[(c - 1) % 3], c, __ATOMIC_RELEASE,
                             __HIP_MEMORY_SCOPE_WORKGROUP);
      }
    }
    asm volatile("s_waitcnt vmcnt(0)" ::: "memory");
    {
      int* fl = p ? flagB : flagA;
      if (lane == 0)
        __hip_atomic_store(&fl[(NCH - 1) % 3], NCH, __ATOMIC_RELEASE,
                           __HIP_MEMORY_SCOPE_WORKGROUP);
    }
  } else {
    // ================= CONSUMER (waves 0..3) =================
    const int mi = wv >> 1;            // row half
    const int ni = wv & 1;             // expert half (2 nt-frags)
    f32x4 accp[2], accq[2];
#pragma unroll
    for (int t = 0; t < 2; ++t) {
      accp[t] = (f32x4){0.f, 0.f, 0.f, 0.f};
      accq[t] = (f32x4){0.f, 0.f, 0.f, 0.f};
    }
#pragma unroll 1
    for (int c = 0; c < NCH; ++c) {
      const int sl = c % 3;
      while (__hip_atomic_load(&flagA[sl], __ATOMIC_ACQUIRE,
                               __HIP_MEMORY_SCOPE_WORKGROUP) < c + 1 ||
             __hip_atomic_load(&flagB[sl], __ATOMIC_ACQUIRE,
                               __HIP_MEMORY_SCOPE_WORKGROUP) < c + 1)
        __builtin_amdgcn_s_sleep(1);
      char* slot = LDS + sl * SLOTB;
#pragma unroll
      for (int ks = 0; ks < 4; ++ks) {
        const float4 xa0 =
            *(const float4*)(slot + ((ks * 4 + mi * 2 + 0) * 64 + lane) * 16);
        const float4 xa1 =
            *(const float4*)(slot + ((ks * 4 + mi * 2 + 1) * 64 + lane) * 16);
        f16x8 ah, al;
        CVT8(ah, al, xa0, xa1);
#pragma unroll
        for (int t = 0; t < 2; ++t) {
          const int v = ks * 4 + ni * 2 + t;
          const f16x8 wh = *(const f16x8*)(slot + 16384 + (v * 64 + lane) * 16);
          const f16x8 wl = *(const f16x8*)(slot + 32768 + (v * 64 + lane) * 16);
          accp[t] = __builtin_amdgcn_mfma_f32_16x16x32_f16(ah, wh, accp[t], 0, 0, 0);
          accq[t] = __builtin_amdgcn_mfma_f32_16x16x32_f16(ah, wl, accq[t], 0, 0, 0);
          accq[t] = __builtin_amdgcn_mfma_f32_16x16x32_f16(al, wh, accq[t], 0, 0, 0);
        }
      }
      asm volatile("s_waitcnt lgkmcnt(0)" ::: "memory");  // slot reads done
      if (lane == 0)
        __hip_atomic_fetch_add(&done[sl], 1, __ATOMIC_RELEASE,
                               __HIP_MEMORY_SCOPE_WORKGROUP);
    }
    // park accumulators until after the barrier (written below)
    __asm__ volatile("" ::
        "v"(accp[0]), "v"(accp[1]), "v"(accq[0]), "v"(accq[1]));
    // write logits into slot0 overlay AFTER barrier
    __syncthreads();
    float* logitp = (float*)LDS;                 // [32][64]
#pragma unroll
    for (int t = 0; t < 2; ++t) {
      const f32x4 accf = accp[t] + accq[t];
#pragma unroll
      for (int r = 0; r < 4; ++r)
        logitp[(mi * 16 + lhi * 4 + r) * 64 + ni * 32 + t * 16 + l15] = accf[r];
    }
    goto epilogue_sync;
  }
  __syncthreads();                               // producers join here
epilogue_sync:
  __syncthreads();

  // ---- softmax/top-2/renorm (verified r6-r16): waves 0..3, 8 rows each ----
  {
    float* logitp = (float*)LDS;                 // [32][64]
    float* simpp  = (float*)(LDS + 8192);        // [4][64]
    float impacc = 0.f;
    if (wv < 4) {
#pragma unroll 1
      for (int i = 0; i < 8; ++i) {
        const int rl  = wv * 8 + i;
        const int row = rb + rl;
        const float lg = logitp[rl * 64 + lane];

        float m = lg;
#pragma unroll
        for (int d = 1; d < 64; d <<= 1) m = fmaxf(m, __shfl_xor(m, d));
        float p = expf(lg - m);
        float s = p;
#pragma unroll
        for (int d = 1; d < 64; d <<= 1) s += __shfl_xor(s, d);
        const float gate = p / s;
        impacc += gate;

        const unsigned long long key =
            ((unsigned long long)__float_as_uint(gate) << 32) | (unsigned)(63 - lane);
        unsigned long long k1 = key;
#pragma unroll
        for (int d = 1; d < 64; d <<= 1) {
          unsigned long long o = __shfl_xor(k1, d);
          if (o > k1) k1 = o;
        }
        const int e1 = 63 - (int)(k1 & 63ull);
        unsigned long long k2 = (lane == e1) ? 0ull : key;
#pragma unroll
        for (int d = 1; d < 64; d <<= 1) {
          unsigned long long o = __shfl_xor(k2, d);
          if (o > k2) k2 = o;
        }
        const int e2 = 63 - (int)(k2 & 63ull);

        if (lane == 0) {
          const float g1 = __uint_as_float((unsigned)(k1 >> 32));
          const float g2 = __uint_as_float((unsigned)(k2 >> 32));
          const float tt  = expf(g2 - g1);          // g1 >= g2
          const float inv = 1.f / (1.f + tt);
          out[(size_t)row * 2]     = inv;
          out[(size_t)row * 2 + 1] = tt * inv;
          out[(size_t)NROWS * 2 + row * 2]     = (float)e1;
          out[(size_t)NROWS * 2 + row * 2 + 1] = (float)e2;
        }
      }
      simpp[wv * 64 + lane] = impacc;
    }
    __syncthreads();

    // ---- importance atomics + last-block aux (verified r12/r14/r16) ----
    if (tid < NE) {
      const float v = (simpp[0 * 64 + tid] + simpp[1 * 64 + tid]) +
                      (simpp[2 * 64 + tid] + simpp[3 * 64 + tid]);
      atomicAdd(&imp[tid], v);
    }
    __syncthreads();

    if (tid == 0) {
      const unsigned old = atomicAdd(cnt, 1u);
      lastflag = (old == 255u) ? 1 : 0;
    }
    __syncthreads();

    if (lastflag && tid < NE) {
      const float v = atomicAdd(&imp[tid], 0.f);   // device-scope read
      float s = v;
#pragma unroll
      for (int d = 1; d < 64; d <<= 1) s += __shfl_xor(s, d);
      const float mean = s / 64.f;
      const float dv = v - mean;
      float sq = dv * dv;
#pragma unroll
      for (int d = 1; d < 64; d <<= 1) sq += __shfl_xor(sq, d);
      const float stdv = sqrtf(sq / 63.f);  // unbiased (E-1)
      const float r = stdv / (mean + 1e-6f);
      if (tid == 0) out[(size_t)NROWS * 4] = r * r;  // d_out[32768]
    }
  }
}

// ---------------------------------------------------------------------------
extern "C" void kernel_launch(void* const* d_in, const int* in_sizes, int n_in,
                              void* d_out, int out_size, void* d_ws, size_t ws_size,
                              hipStream_t stream) {
  const float* x = (const float*)d_in[0];
  const float* W = (const float*)d_in[1];
  float* out  = (float*)d_out;
  _Float16* Whi = (_Float16*)d_ws;                 // 512 KB
  _Float16* Wlo = Whi + (size_t)NE * NK;           // 512 KB
  float* imp  = (float*)(Wlo + (size_t)NE * NK);   // 64 f32
  unsigned* cnt = (unsigned*)(imp + NE);           // 1 u32

  hipLaunchKernelGGL(k_prep,  dim3(1024), dim3(256), 0, stream, W, Whi, Wlo, imp, cnt);
  hipLaunchKernelGGL(k_fused, dim3(256),  dim3(384), 0, stream, x, Whi, Wlo, out, imp, cnt);
}